// Round 2
// baseline (240.010 us; speedup 1.0000x reference)
//
#include <hip/hip_runtime.h>

#define N_SAMP   1024
#define IN_F     512
#define OUT_F    512
#define N_HEADS  32
#define N_SPLITS 4
#define N_GROUPS (N_HEADS * N_SPLITS)
#define DELTA_SCALE 0.1f

// R7: fused single-pass by (head,split) combo.
//   block = (combo g = h*4+s, 64-col tile)   grid = (8, 128) = 1024 blocks
//   thread = (c2 = col-pair 0..31, kq = k-eighth 0..7), 256 threads
//
// Replaces the two-pass base+delta structure. Each block streams BOTH the
// W[h] column stripe and the D[g] column stripe (8 float2 loads in flight
// per 4-row step -> 2x deeper natural pipeline than the old passes),
// combines rc = w + 0.1*d once per step (8 v_fma amortized over J*8 fmac),
// and runs ONE GEMV per sample against the combined weight -> halves the
// per-sample FMA work vs base+delta. out is written exactly once with bias
// folded in: no RMW read-back, no inter-kernel serialization, and no
// early-exit occupancy holes (every combo has ~8 samples; uniform 4
// blocks/CU at 36.9 KB LDS -> 16 waves/CU steady).
//
// Deterministic order-preserving compaction retained from R6 (all 8
// tile-blocks of a combo derive the identical list; tiles partition cols,
// so every output element is written exactly once).
__global__ __launch_bounds__(256, 4) void lms_fused(
    const float* __restrict__ X, const int* __restrict__ head_ix,
    const int* __restrict__ split_ix, const float* __restrict__ W,
    const float* __restrict__ D, const float* __restrict__ bias,
    float* __restrict__ out)
{
    constexpr int J    = 16;           // samples per chunk (mean 8 per combo)
    constexpr int KQ   = 8;            // k-split ways
    constexpr int KT   = IN_F / KQ;    // 64 k rows per thread
    constexpr int NST  = KT / 4;       // 16 steps of 4 rows
    constexpr int NOUT = (J * 32) / 256;  // 2

    __shared__ float buf[J * IN_F];    // Xs[J][512] <-> Red[KQ][J][32] float2
    __shared__ int   list[N_SAMP];
    __shared__ int   wsum[4];

    const int g    = blockIdx.y;           // combo = h*N_SPLITS + s
    const int h    = g / N_SPLITS;
    const int c0   = blockIdx.x * 64;
    const int tid  = threadIdx.x;
    const int c2   = tid & 31;             // col pair
    const int kq   = tid >> 5;             // k-eighth
    const int lane = tid & 63;
    const int wave = tid >> 6;

    // deterministic order-preserving compaction of samples matching combo g
    int run = 0;
    for (int r = 0; r < N_SAMP / 256; ++r) {
        const int i   = r * 256 + tid;
        const int key = head_ix[i] * N_SPLITS + split_ix[i];
        const bool hit = (key == g);
        const unsigned long long m = __ballot(hit);
        if (lane == 0) wsum[wave] = __popcll(m);
        __syncthreads();
        int base = run;
        for (int w = 0; w < 4; ++w)
            if (w < wave) base += wsum[w];
        if (hit)
            list[base + __popcll(m & ((1ULL << lane) - 1ULL))] = i;
        run += wsum[0] + wsum[1] + wsum[2] + wsum[3];
        __syncthreads();               // wsum consumed before next round
    }
    const int total = run;
    if (total == 0) return;            // block-uniform

    // thread's stripes: rows kq*KT .. kq*KT+63, cols c0+2*c2 (+1)
    const size_t roff = (size_t)(kq * KT) * OUT_F + c0 + c2 * 2;
    const float* wp = W + (size_t)h * (IN_F * OUT_F) + roff;
    const float* dp = D + (size_t)g * (IN_F * OUT_F) + roff;

    for (int s0 = 0; s0 < total; s0 += J) {
        const int nc = min(total - s0, J);

        __syncthreads();               // buf may still hold previous Red
        for (int i = tid; i < J * (IN_F / 4); i += 256) {
            const int s = i >> 7, q = i & 127;
            float4 v = make_float4(0.f, 0.f, 0.f, 0.f);
            if (s < nc)
                v = *(const float4*)(X + (size_t)list[s0 + s] * IN_F + q * 4);
            *(float4*)(&buf[s * IN_F + q * 4]) = v;
        }
        __syncthreads();

        float2 acc[J];
#pragma unroll
        for (int j = 0; j < J; ++j) { acc[j].x = 0.f; acc[j].y = 0.f; }

        // distance-1 double-buffered 4-row batches of BOTH W and D
        float2 wb[2][4], db[2][4];
#pragma unroll
        for (int u = 0; u < 4; ++u) {
            wb[0][u] = *(const float2*)(wp + (size_t)u * OUT_F);
            db[0][u] = *(const float2*)(dp + (size_t)u * OUT_F);
        }

#pragma unroll 2
        for (int st = 0; st < NST; ++st) {
            // prefetch next 4-row batch (clamped tail: redundant L1-hit
            // re-load keeps the body branch-free)
            const int nx = (st + 1 < NST) ? st + 1 : NST - 1;
            const int nb = (st + 1) & 1, cb = st & 1;
            const float* wn = wp + (size_t)(nx * 4) * OUT_F;
            const float* dn = dp + (size_t)(nx * 4) * OUT_F;
#pragma unroll
            for (int u = 0; u < 4; ++u) {
                wb[nb][u] = *(const float2*)(wn + (size_t)u * OUT_F);
                db[nb][u] = *(const float2*)(dn + (size_t)u * OUT_F);
            }

            // combined weight for this 4-row batch (amortized over J fmacs)
            float2 rc[4];
#pragma unroll
            for (int u = 0; u < 4; ++u) {
                rc[u].x = wb[cb][u].x + DELTA_SCALE * db[cb][u].x;
                rc[u].y = wb[cb][u].y + DELTA_SCALE * db[cb][u].y;
            }

            const float* xb = &buf[kq * KT + st * 4];
#pragma unroll
            for (int j = 0; j < J; ++j) {
                const float4 xv = *(const float4*)(xb + j * IN_F); // broadcast
                acc[j].x += xv.x * rc[0].x; acc[j].y += xv.x * rc[0].y;
                acc[j].x += xv.y * rc[1].x; acc[j].y += xv.y * rc[1].y;
                acc[j].x += xv.z * rc[2].x; acc[j].y += xv.z * rc[2].y;
                acc[j].x += xv.w * rc[3].x; acc[j].y += xv.w * rc[3].y;
            }
        }

        __syncthreads();               // Xs fully consumed; reuse buf as Red
        float2* Red = (float2*)buf;    // [KQ][J][32]
#pragma unroll
        for (int j = 0; j < J; ++j)
            Red[(kq * J + j) * 32 + c2] = acc[j];
        __syncthreads();

        // sole-owner epilogue: sum the 8 k-partials, add bias, pure store
#pragma unroll
        for (int t = 0; t < NOUT; ++t) {
            const int oi = t * 256 + tid;
            const int j = oi >> 5, cc = oi & 31;
            if (j < nc) {
                float2 s = make_float2(0.f, 0.f);
#pragma unroll
                for (int q = 0; q < KQ; ++q) {
                    const float2 r = Red[(q * J + j) * 32 + cc];
                    s.x += r.x; s.y += r.y;
                }
                const float2 bv =
                    *(const float2*)(bias + (size_t)h * OUT_F + c0 + cc * 2);
                float* op = out + (size_t)list[s0 + j] * OUT_F + c0 + cc * 2;
                float2 res;
                res.x = s.x + bv.x;
                res.y = s.y + bv.y;
                *(float2*)op = res;
            }
        }
    }
}

extern "C" void kernel_launch(void* const* d_in, const int* in_sizes, int n_in,
                              void* d_out, int out_size, void* d_ws, size_t ws_size,
                              hipStream_t stream) {
    const float* X        = (const float*)d_in[0];
    const int*   head_ix  = (const int*)d_in[1];
    const int*   split_ix = (const int*)d_in[2];
    const float* W        = (const float*)d_in[3];
    const float* D        = (const float*)d_in[4];
    const float* bias     = (const float*)d_in[5];
    float*       out      = (float*)d_out;

    // 128 combos x 8 col-tiles = 1024 blocks = 4/CU (36.9 KB LDS),
    // 16 waves/CU uniform. Single dispatch: no base->delta serialization,
    // no out RMW, every output written exactly once (bias folded in).
    dim3 gf(OUT_F / 64, N_GROUPS);
    lms_fused<<<gf, 256, 0, stream>>>(X, head_ix, split_ix, W, D, bias, out);
}